// Round 2
// 336.221 us; speedup vs baseline: 1.1108x; 1.1108x over previous
//
#include <hip/hip_runtime.h>
#include <hip/hip_bf16.h>

#define N_NODES 20000
#define N_EDGES 640000
#define D_NODE  128
#define D_EDGE  64
#define D_OUT   128

// round-to-nearest-even fp32 -> bf16 bits
__device__ __forceinline__ unsigned short f2bf(float x) {
    unsigned u = __float_as_uint(x);
    unsigned r = ((u >> 16) & 1u) + 0x7FFFu;
    return (unsigned short)((u + r) >> 16);
}
__device__ __forceinline__ float bf2f(unsigned short b) {
    return __uint_as_float((unsigned)b << 16);
}

// ---------------------------------------------------------------------------
// k_init_prep: blocks 0..78 zero deg; block 79 builds WnT (transpose) and
// ce = We^T a_e.
// ---------------------------------------------------------------------------
__global__ __launch_bounds__(256) void k_init_prep(const float* __restrict__ Wn,
                                                   const float* __restrict__ We,
                                                   const float* __restrict__ Wa,
                                                   int* __restrict__ deg,
                                                   float* __restrict__ WnT,
                                                   float* __restrict__ ce) {
    int t = threadIdx.x, b = blockIdx.x;
    if (b < 79) {
        int i = b * 256 + t;
        if (i < N_NODES) deg[i] = 0;
    } else {
        for (int idx = t; idx < D_OUT * D_NODE; idx += 256) {
            int o = idx >> 7, k = idx & 127;
            WnT[k * D_OUT + o] = Wn[idx];
        }
        if (t < D_EDGE) {
            float a = 0.f;
            for (int o = 0; o < D_OUT; ++o)
                a += Wa[2 * D_OUT + o] * We[o * D_EDGE + t];
            ce[t] = a;
        }
    }
}

// ---------------------------------------------------------------------------
// k_fused: blocks [0,625)      = zgemm (z in bf16, fused fp32 ssrc/sdst);
//          blocks [625,10625)  = edge stream: ge[j] = fe[j].ce (164 MB read,
//                                the pipeline's dominant stream, hoisted here
//                                so it overlaps the compute-bound GEMM) plus
//                                dst histogram + per-edge rank (atomic-return
//                                latency hides under the stream).
// LDS cut 48->32 KB (sW now 32x128, 4 phases) => 5 blocks/CU for the
// streaming blocks. Accumulation order identical to the 2-phase version.
// ---------------------------------------------------------------------------
__global__ __launch_bounds__(256) void k_fused(const float* __restrict__ feats,
                                               const float* __restrict__ wT,
                                               const float* __restrict__ Wa,
                                               const float* __restrict__ fe,
                                               const float* __restrict__ ce,
                                               const int* __restrict__ dst,
                                               unsigned short* __restrict__ zb,
                                               float* __restrict__ ssrc,
                                               float* __restrict__ sdst,
                                               int* __restrict__ deg,
                                               int* __restrict__ rank,
                                               float* __restrict__ ge) {
    __shared__ float sW[32 * 128];
    __shared__ float sF[32 * 128];
    int t = threadIdx.x;

    if (blockIdx.x >= 625) {
        // 64 edges per block, 4 threads per edge, fully coalesced.
        int b = blockIdx.x - 625;
        int j = b * 64 + (t >> 2);
        int part = t & 3;
        const float4* row = (const float4*)(fe + (size_t)j * D_EDGE + part * 16);
        const float4* c4 = (const float4*)(ce + part * 16);
        float acc = 0.f;
#pragma unroll
        for (int i = 0; i < 4; ++i) {
            float4 f = row[i];
            float4 c = c4[i];
            acc += f.x * c.x + f.y * c.y + f.z * c.z + f.w * c.w;
        }
        acc += __shfl_xor(acc, 1, 64);
        acc += __shfl_xor(acc, 2, 64);
        if (part == 0) {
            ge[j] = acc;
            rank[j] = atomicAdd(&deg[dst[j]], 1);
        }
        return;
    }

    int nb = blockIdx.x * 32;
    const float4* fsrc = (const float4*)(feats + (size_t)nb * D_NODE);
    float4* fdst = (float4*)sF;
    for (int i = t; i < 32 * 32; i += 256) fdst[i] = fsrc[i];

    float acc[4][4] = {{0.f}};
    int o0 = (t & 31) * 4;
    int n0 = (t >> 5) * 4;

    for (int p = 0; p < 4; ++p) {
        __syncthreads();
        const float4* wsrc = (const float4*)(wT + p * 32 * 128);
        float4* wdst = (float4*)sW;
        for (int i = t; i < 32 * 32; i += 256) wdst[i] = wsrc[i];
        __syncthreads();
        for (int kk = 0; kk < 32; kk += 4) {
            float4 w0 = *(const float4*)(sW + (kk + 0) * 128 + o0);
            float4 w1 = *(const float4*)(sW + (kk + 1) * 128 + o0);
            float4 w2 = *(const float4*)(sW + (kk + 2) * 128 + o0);
            float4 w3 = *(const float4*)(sW + (kk + 3) * 128 + o0);
#pragma unroll
            for (int j = 0; j < 4; ++j) {
                float4 f = *(const float4*)(sF + (n0 + j) * 128 + p * 32 + kk);
                acc[j][0] += f.x * w0.x + f.y * w1.x + f.z * w2.x + f.w * w3.x;
                acc[j][1] += f.x * w0.y + f.y * w1.y + f.z * w2.y + f.w * w3.y;
                acc[j][2] += f.x * w0.z + f.y * w1.z + f.z * w2.z + f.w * w3.z;
                acc[j][3] += f.x * w0.w + f.y * w1.w + f.z * w2.w + f.w * w3.w;
            }
        }
    }

    float as0 = Wa[o0 + 0], as1 = Wa[o0 + 1], as2 = Wa[o0 + 2], as3 = Wa[o0 + 3];
    float ad0 = Wa[128 + o0 + 0], ad1 = Wa[128 + o0 + 1],
          ad2 = Wa[128 + o0 + 2], ad3 = Wa[128 + o0 + 3];
#pragma unroll
    for (int j = 0; j < 4; ++j) {
        int n = nb + n0 + j;
        ushort4 zo;
        zo.x = f2bf(acc[j][0]); zo.y = f2bf(acc[j][1]);
        zo.z = f2bf(acc[j][2]); zo.w = f2bf(acc[j][3]);
        *(ushort4*)(zb + (size_t)n * D_OUT + o0) = zo;
        float ps = acc[j][0] * as0 + acc[j][1] * as1 + acc[j][2] * as2 + acc[j][3] * as3;
        float pd = acc[j][0] * ad0 + acc[j][1] * ad1 + acc[j][2] * ad2 + acc[j][3] * ad3;
#pragma unroll
        for (int off = 16; off; off >>= 1) {
            ps += __shfl_xor(ps, off, 32);
            pd += __shfl_xor(pd, off, 32);
        }
        if ((t & 31) == 0) { ssrc[n] = ps; sdst[n] = pd; }
    }
}

// ---------------------------------------------------------------------------
// k_scan: single-round thread-coarsened exclusive scan (1024 x 20 elems).
// ---------------------------------------------------------------------------
__global__ __launch_bounds__(1024) void k_scan(const int* __restrict__ deg,
                                               int* __restrict__ offsets) {
    __shared__ int wsum[16];
    __shared__ int woff[16];
    const int PER = 20;
    int t = threadIdx.x, lane = t & 63, wv = t >> 6;
    int base = t * PER;
    int v[PER];
    int tsum = 0;
#pragma unroll
    for (int i = 0; i < PER; ++i) {
        int idx = base + i;
        v[i] = (idx < N_NODES) ? deg[idx] : 0;
        tsum += v[i];
    }
    int x = tsum;
#pragma unroll
    for (int d = 1; d < 64; d <<= 1) {
        int y = __shfl_up(x, d, 64);
        if (lane >= d) x += y;
    }
    if (lane == 63) wsum[wv] = x;
    __syncthreads();
    if (t == 0) {
        int a = 0;
        for (int i = 0; i < 16; ++i) { int tmp = wsum[i]; woff[i] = a; a += tmp; }
        offsets[N_NODES] = a;
    }
    __syncthreads();
    int run = (x - tsum) + woff[wv];
#pragma unroll
    for (int i = 0; i < PER; ++i) {
        int idx = base + i;
        if (idx < N_NODES) offsets[idx] = run;
        run += v[i];
    }
}

// ---------------------------------------------------------------------------
// k_place: light CSR placement. One thread per edge; reads only the small
// per-edge arrays (ge/src/dst/rank ~ 10 MB) + L2-resident gathers; the heavy
// fe stream already happened inside k_fused. One 8B scatter store per edge.
// ---------------------------------------------------------------------------
__global__ __launch_bounds__(256) void k_place(const float* __restrict__ ge,
                                               const float* __restrict__ ssrc,
                                               const float* __restrict__ sdst,
                                               const int* __restrict__ src,
                                               const int* __restrict__ dst,
                                               const int* __restrict__ rank,
                                               const int* __restrict__ offsets,
                                               float2* __restrict__ es) {
    int j = blockIdx.x * 256 + threadIdx.x;
    int sj = src[j], dj = dst[j];
    float x = ge[j] + ssrc[sj] + sdst[dj];
    float ev = x > 0.f ? x : 0.2f * x;
    int pos = offsets[dj] + rank[j];
    es[pos] = make_float2(ev, __int_as_float(sj));
}

// ---------------------------------------------------------------------------
// k_gather: one wave per node, zero barriers/LDS. Softmax weights from fp32
// logits; aggregation gathers bf16 z rows (64 lanes x ushort2 = 256B/edge).
// 4 nodes per 256-thread block.
// ---------------------------------------------------------------------------
__global__ __launch_bounds__(256) void k_gather(const int* __restrict__ offsets,
                                                const float2* __restrict__ es,
                                                const unsigned short* __restrict__ zb,
                                                float* __restrict__ h) {
    int lane = threadIdx.x & 63;
    int n = blockIdx.x * 4 + (threadIdx.x >> 6);
    int beg = offsets[n], end = offsets[n + 1];

    float2 v0 = make_float2(-3.4e38f, 0.f);
    int i0 = beg + lane;
    if (i0 < end) v0 = es[i0];
    float lmax = v0.x;
    for (int base = beg + 64; base < end; base += 64) {
        int i = base + lane;
        lmax = fmaxf(lmax, (i < end) ? es[i].x : -3.4e38f);
    }
#pragma unroll
    for (int off = 32; off; off >>= 1) lmax = fmaxf(lmax, __shfl_xor(lmax, off, 64));
    float m = lmax;

    float w0 = (i0 < end) ? __expf(v0.x - m) : 0.f;
    float lsum = w0;
    for (int base = beg + 64; base < end; base += 64) {
        int i = base + lane;
        lsum += (i < end) ? __expf(es[i].x - m) : 0.f;
    }
#pragma unroll
    for (int off = 32; off; off >>= 1) lsum += __shfl_xor(lsum, off, 64);
    float inv = (lsum > 0.f) ? 1.f / lsum : 0.f;

    float accx = 0.f, accy = 0.f;
    {
        int cnt = min(64, end - beg);
        float wl = w0 * inv;
        int sl = __float_as_int(v0.y);
        int r = 0;
        for (; r + 4 <= cnt; r += 4) {
            float wr0 = __shfl(wl, r + 0, 64); int sr0 = __shfl(sl, r + 0, 64);
            float wr1 = __shfl(wl, r + 1, 64); int sr1 = __shfl(sl, r + 1, 64);
            float wr2 = __shfl(wl, r + 2, 64); int sr2 = __shfl(sl, r + 2, 64);
            float wr3 = __shfl(wl, r + 3, 64); int sr3 = __shfl(sl, r + 3, 64);
            ushort2 z0 = *(const ushort2*)(zb + (size_t)sr0 * D_OUT + lane * 2);
            ushort2 z1 = *(const ushort2*)(zb + (size_t)sr1 * D_OUT + lane * 2);
            ushort2 z2 = *(const ushort2*)(zb + (size_t)sr2 * D_OUT + lane * 2);
            ushort2 z3 = *(const ushort2*)(zb + (size_t)sr3 * D_OUT + lane * 2);
            accx += wr0 * bf2f(z0.x) + wr1 * bf2f(z1.x) + wr2 * bf2f(z2.x) + wr3 * bf2f(z3.x);
            accy += wr0 * bf2f(z0.y) + wr1 * bf2f(z1.y) + wr2 * bf2f(z2.y) + wr3 * bf2f(z3.y);
        }
        for (; r < cnt; ++r) {
            float wr = __shfl(wl, r, 64); int sr = __shfl(sl, r, 64);
            ushort2 zv = *(const ushort2*)(zb + (size_t)sr * D_OUT + lane * 2);
            accx += wr * bf2f(zv.x); accy += wr * bf2f(zv.y);
        }
    }
    for (int base = beg + 64; base < end; base += 64) {
        int i = base + lane;
        float2 v = (i < end) ? es[i] : make_float2(0.f, 0.f);
        float wl = (i < end) ? __expf(v.x - m) * inv : 0.f;
        int sl = __float_as_int(v.y);
        int cnt = min(64, end - base);
        int r = 0;
        for (; r + 4 <= cnt; r += 4) {
            float wr0 = __shfl(wl, r + 0, 64); int sr0 = __shfl(sl, r + 0, 64);
            float wr1 = __shfl(wl, r + 1, 64); int sr1 = __shfl(sl, r + 1, 64);
            float wr2 = __shfl(wl, r + 2, 64); int sr2 = __shfl(sl, r + 2, 64);
            float wr3 = __shfl(wl, r + 3, 64); int sr3 = __shfl(sl, r + 3, 64);
            ushort2 z0 = *(const ushort2*)(zb + (size_t)sr0 * D_OUT + lane * 2);
            ushort2 z1 = *(const ushort2*)(zb + (size_t)sr1 * D_OUT + lane * 2);
            ushort2 z2 = *(const ushort2*)(zb + (size_t)sr2 * D_OUT + lane * 2);
            ushort2 z3 = *(const ushort2*)(zb + (size_t)sr3 * D_OUT + lane * 2);
            accx += wr0 * bf2f(z0.x) + wr1 * bf2f(z1.x) + wr2 * bf2f(z2.x) + wr3 * bf2f(z3.x);
            accy += wr0 * bf2f(z0.y) + wr1 * bf2f(z1.y) + wr2 * bf2f(z2.y) + wr3 * bf2f(z3.y);
        }
        for (; r < cnt; ++r) {
            float wr = __shfl(wl, r, 64); int sr = __shfl(sl, r, 64);
            ushort2 zv = *(const ushort2*)(zb + (size_t)sr * D_OUT + lane * 2);
            accx += wr * bf2f(zv.x); accy += wr * bf2f(zv.y);
        }
    }
    *(float2*)(h + (size_t)n * D_OUT + lane * 2) = make_float2(accx, accy);
}

extern "C" void kernel_launch(void* const* d_in, const int* in_sizes, int n_in,
                              void* d_out, int out_size, void* d_ws, size_t ws_size,
                              hipStream_t stream) {
    const float* feats_node = (const float*)d_in[0];
    const float* feats_edge = (const float*)d_in[1];
    const float* Wn = (const float*)d_in[2];
    const float* We = (const float*)d_in[3];
    const float* Wa = (const float*)d_in[4];
    const int* src = (const int*)d_in[5];
    const int* dst = (const int*)d_in[6];
    float* h = (float*)d_out;

    // workspace layout
    float* WnT  = (float*)d_ws;                       // 16384 f
    float* ce   = WnT + 16384;                        // 64 f
    float* ssrc = ce + 64;                            // 20000 f
    float* sdst = ssrc + N_NODES;                     // 20000 f
    float2* es  = (float2*)(sdst + N_NODES);          // 640000 float2 (8B-aligned)
    unsigned short* zb = (unsigned short*)(es + N_EDGES); // 2,560,000 ushort
    int* deg     = (int*)(zb + (size_t)N_NODES * D_OUT);  // 20000
    int* offsets = deg + N_NODES;                     // 20001
    int* rank    = offsets + N_NODES + 1;             // 640000
    float* ge    = (float*)(rank + N_EDGES);          // 640000 f

    k_init_prep<<<80, 256, 0, stream>>>(Wn, We, Wa, deg, WnT, ce);
    k_fused<<<625 + N_EDGES / 64, 256, 0, stream>>>(feats_node, WnT, Wa, feats_edge, ce,
                                                    dst, zb, ssrc, sdst, deg, rank, ge);
    k_scan<<<1, 1024, 0, stream>>>(deg, offsets);
    k_place<<<N_EDGES / 256, 256, 0, stream>>>(ge, ssrc, sdst, src, dst, rank, offsets, es);
    k_gather<<<N_NODES / 4, 256, 0, stream>>>(offsets, es, zb, h);
}